// Round 12
// baseline (293.488 us; speedup 1.0000x reference)
//
#include <hip/hip_runtime.h>
#include <math.h>

#define DEV_INLINE __device__ __forceinline__

constexpr int B = 8, S = 1536, IN = 32, D = 128, NH = 4, KWIN = 7, NLVL = 2;
constexpr int DFF = 512, DKH = 32;
constexpr int M = B * S;           // 12288 rows
constexpr int MD = M * D;          // 1572864
constexpr float EPS = 1e-6f;
constexpr float LOG2E = 1.4426950408889634f;

typedef unsigned short u16;
typedef __bf16 bf16x8 __attribute__((ext_vector_type(8)));
typedef float f32x4 __attribute__((ext_vector_type(4)));
typedef unsigned short u16x4 __attribute__((ext_vector_type(4)));

#define MFMA16(a, b, c) __builtin_amdgcn_mfma_f32_16x16x32_bf16(a, b, c, 0, 0, 0)

DEV_INLINE float frcp(float x) { return __builtin_amdgcn_rcpf(x); }
DEV_INLINE float fexp2(float x) { return __builtin_amdgcn_exp2f(x); }
DEV_INLINE float sigmoidf_(float x) { return 1.f / (1.f + __expf(-x)); }
// fast sigmoid/tanh: rcp+exp2 (error ~1e-7 rel, far below bf16 rounding)
DEV_INLINE float fsigmoid(float x) { return frcp(1.f + fexp2(-LOG2E * x)); }
DEV_INLINE float ftanh(float x) { return 1.f - 2.f * frcp(fexp2(2.f * LOG2E * x) + 1.f); }

DEV_INLINE u16 f2bf(float f) {
    unsigned u = __builtin_bit_cast(unsigned, f);
    unsigned rnd = 0x7FFFu + ((u >> 16) & 1u);
    return (u16)((u + rnd) >> 16);
}
DEV_INLINE float b2f(u16 v) { return __builtin_bit_cast(float, (unsigned)v << 16); }

// shared 32x32-tile K-loop (A rows / Bt rows both [.][KDIM] bf16, global)
template <int KDIM>
DEV_INLINE void mfma_tile32(const u16* a0p, const u16* a1p, const u16* b0p, const u16* b1p,
                            f32x4& acc00, f32x4& acc01, f32x4& acc10, f32x4& acc11) {
    #pragma unroll
    for (int k0 = 0; k0 < KDIM; k0 += 32) {
        bf16x8 a0 = *(const bf16x8*)(a0p + k0);
        bf16x8 a1 = *(const bf16x8*)(a1p + k0);
        bf16x8 b0 = *(const bf16x8*)(b0p + k0);
        bf16x8 b1 = *(const bf16x8*)(b1p + k0);
        acc00 = MFMA16(a0, b0, acc00);
        acc01 = MFMA16(a0, b1, acc01);
        acc10 = MFMA16(a1, b0, acc10);
        acc11 = MFMA16(a1, b1, acc11);
    }
}

// ---------------------------------------------------------------- weight prep + encoder (merged)
__global__ __launch_bounds__(256) void k_prep_enc(
    const float* __restrict__ Wih, const float* __restrict__ Whh,
    const float* __restrict__ Wq, const float* __restrict__ Wk,
    const float* __restrict__ Wv, const float* __restrict__ Wo,
    const float* __restrict__ W1, const float* __restrict__ W2,
    u16* __restrict__ Wih16, u16* __restrict__ Whh16,
    u16* __restrict__ Wqkv, u16* __restrict__ WoT,
    u16* __restrict__ W1T, u16* __restrict__ W2T,
    const float* __restrict__ x, const float* __restrict__ encW, const float* __restrict__ encb,
    const float* __restrict__ ga, const float* __restrict__ gb,
    float* __restrict__ h, u16* __restrict__ xnout) {
    __shared__ float xs[32][33];
    __shared__ float Ws[32][128];
    const int tid = threadIdx.x;
    if (blockIdx.x < 2304) {
        constexpr int SZ_GRU = NLVL * 384 * 128;   // 98304
        constexpr int SZ_DD  = NLVL * 128 * 128;   // 32768
        constexpr int SZ_FF  = NLVL * 128 * 512;   // 131072
        int i = blockIdx.x * 256 + tid;
        if (i < SZ_GRU) { Wih16[i] = f2bf(Wih[i]); return; }
        i -= SZ_GRU;
        if (i < SZ_GRU) { Whh16[i] = f2bf(Whh[i]); return; }
        i -= SZ_GRU;
        if (i < 3 * SZ_DD) {  // Wq/Wk/Wv [lvl][k][n] -> Wqkv[lvl][seg*128+n][k]
            int seg = i / SZ_DD, j = i - seg * SZ_DD;
            int lvl = j >> 14, rem = j & 16383, k = rem >> 7, n = rem & 127;
            const float* src = seg == 0 ? Wq : (seg == 1 ? Wk : Wv);
            Wqkv[(size_t)lvl * 384 * 128 + (size_t)(seg * 128 + n) * 128 + k] = f2bf(src[j]);
            return;
        }
        i -= 3 * SZ_DD;
        if (i < SZ_DD) {      // Wo [lvl][k][n] -> [lvl][n][k]
            int lvl = i >> 14, rem = i & 16383, k = rem >> 7, n = rem & 127;
            WoT[(size_t)lvl * 16384 + n * 128 + k] = f2bf(Wo[i]); return;
        }
        i -= SZ_DD;
        if (i < SZ_FF) {      // W1 [lvl][k<128][n<512] -> [lvl][n][k]
            int lvl = i >> 16, rem = i & 65535, k = rem >> 9, n = rem & 511;
            W1T[(size_t)lvl * 65536 + n * 128 + k] = f2bf(W1[i]); return;
        }
        i -= SZ_FF;
        if (i < SZ_FF) {      // W2 [lvl][k<512][n<128] -> [lvl][n][k]
            int lvl = i >> 16, rem = i & 65535, k = rem >> 7, n = rem & 127;
            W2T[(size_t)lvl * 65536 + n * 512 + k] = f2bf(W2[i]); return;
        }
        return;
    }
    // ---- encoder path ----
    const int row0 = (blockIdx.x - 2304) * 32;
    for (int i = tid; i < 32 * 32; i += 256) xs[i >> 5][i & 31] = x[(size_t)row0 * IN + i];
    for (int i = tid; i < 32 * 128; i += 256) Ws[i >> 7][i & 127] = encW[i];
    __syncthreads();
    const int r = tid >> 3, cg = (tid & 7) * 16;
    float acc[16];
    #pragma unroll
    for (int j = 0; j < 16; ++j) acc[j] = encb[cg + j];
    for (int k = 0; k < IN; ++k) {
        const float xv = xs[r][k];
        #pragma unroll
        for (int j = 0; j < 16; ++j) acc[j] = fmaf(xv, Ws[k][cg + j], acc[j]);
    }
    float s = 0.f;
    #pragma unroll
    for (int j = 0; j < 16; ++j) s += acc[j];
    s += __shfl_xor(s, 1); s += __shfl_xor(s, 2); s += __shfl_xor(s, 4);
    const float mean = s * (1.f / D);
    float q = 0.f;
    #pragma unroll
    for (int j = 0; j < 16; ++j) { float d = acc[j] - mean; q += d * d; }
    q += __shfl_xor(q, 1); q += __shfl_xor(q, 2); q += __shfl_xor(q, 4);
    const float inv = 1.f / (sqrtf(q * (1.f / (D - 1))) + EPS);
    float* hp = h + (size_t)(row0 + r) * D + cg;
    u16* xp = xnout + (size_t)(row0 + r) * D + cg;
    #pragma unroll
    for (int jj = 0; jj < 4; ++jj) {
        float4 hv = make_float4(acc[4 * jj], acc[4 * jj + 1], acc[4 * jj + 2], acc[4 * jj + 3]);
        *(float4*)(hp + 4 * jj) = hv;
        u16x4 o;
        #pragma unroll
        for (int c = 0; c < 4; ++c)
            o[c] = f2bf(ga[cg + 4 * jj + c] * (acc[4 * jj + c] - mean) * inv + gb[cg + 4 * jj + c]);
        *(u16x4*)(xp + 4 * jj) = o;
    }
}

// ---------------------------------------------------------------- fused windowed GRU + ln_attn + QKV
// 256 blocks x 512 thr; LDS pooled to 81840 B so TWO blocks fit per CU.
//   poolS: [ Gs 54*516 | hsA 48*136 | hsB 48*136 ]; xnS (54*136, phase-1-only)
//   ALIASES hsA/hsB (phase-2-only): t=0 fully overwrites hsA before t=1 reads;
//   hsB's stale prefix is overwritten at t=1 before t=2 reads.
// Phase 1: stage xn rows [row0-6, row0+48); G = xn@Wih^T into 54-row Gs via two
//   overlapping 32-row bands (rows 22..31 written twice with identical values).
//   Gate-interleaved Gs[row][c*4+g] -> one u16x4 gate load per row per step.
// Phase 2: 7-step GRU; Whh B-frags loop-invariant in regs; dbuf hs, 1 barrier/step;
//   fast rcp/exp2 gates.
// Phase 3: residual += into hout; ln_attn -> hsA.  Phase 4: QKV from LDS.
__global__ __launch_bounds__(512, 2) void k_gru_qkv(
    const u16* __restrict__ xn,     // [M][128] bf16 ln_rnn output
    const u16* __restrict__ Wih16,  // [384][128] bf16
    const u16* __restrict__ Whh16,  // [384][128] bf16
    const float* __restrict__ bih, const float* __restrict__ bhh,
    float* __restrict__ hout,       // [M][128] f32 residual (read+write)
    const float* __restrict__ ga, const float* __restrict__ gb,
    const u16* __restrict__ Wqkv,   // [384][128] bf16 (Q|K|V rows)
    const float* __restrict__ bq, const float* __restrict__ bk, const float* __restrict__ bv,
    u16* __restrict__ q16, u16* __restrict__ k16, u16* __restrict__ vt16) {
    constexpr int RB = 48;
    constexpr int GST = 516;                       // Gs stride in u16 (8B-aligned rows)
    constexpr float QS = 0.17677669529663687f * 1.4426950408889634f;  // scale * log2(e)
    __shared__ __align__(16) u16 poolS[54 * GST + 2 * RB * 136];   // 81840 B total
    u16* const Gs  = poolS;                        // 54*516 u16 (55728 B); tail: f32 hf[48][132]
    u16* const hsA = poolS + 54 * GST;             // 48*136 u16
    u16* const hsB = hsA + RB * 136;               // 48*136 u16
    u16* const xnS = hsA;                          // alias: 54*136 u16 spans hsA+prefix of hsB
    const int tid = threadIdx.x;
    const int wave = tid >> 6, lane = tid & 63;
    const int col16 = lane & 15, quad = lane >> 4;
    const int row0 = blockIdx.x * RB;
    const int ss0 = row0 % S;
    const int cc = wave * 16 + col16;      // this thread's h column

    // stage xn rows row0-6 .. row0+47 (54 rows; zero pad before sequence start)
    for (int i = tid; i < 54 * 16; i += 512) {
        const int r = i >> 4, c8 = (i & 15) * 8;
        bf16x8 val = {};
        if (ss0 - 6 + r >= 0)
            val = *(const bf16x8*)(xn + (size_t)(row0 - 6 + r) * 128 + c8);
        *(bf16x8*)&xnS[r * 136 + c8] = val;
    }
    // loop-invariant Whh B-fragments + biases
    bf16x8 Breg[3][4];
    #pragma unroll
    for (int g = 0; g < 3; ++g)
        #pragma unroll
        for (int kc = 0; kc < 4; ++kc)
            Breg[g][kc] = *(const bf16x8*)(Whh16 + (size_t)(g * 128 + cc) * 128 + kc * 32 + quad * 8);
    float bi[3], bh[3];
    #pragma unroll
    for (int g = 0; g < 3; ++g) { bi[g] = bih[g * 128 + cc]; bh[g] = bhh[g * 128 + cc]; }
    __syncthreads();

    // G = xn @ Wih^T : 24 tiles (2 bands x 12 col-tiles); band rows: band*22 .. band*22+31
    // (bands overlap rows 22..31 — written twice with identical values, benign).
    #pragma unroll
    for (int tt = wave; tt < 24; tt += 8) {
        const int rt = tt / 12, ct = tt - rt * 12;
        const int gg = ct >> 2;                 // gate index 0..2
        const int cb = (ct & 3) * 32;           // col base within 128
        const int rb = rt * 22;                 // band row base in Gs/xnS
        const u16* bp = Wih16 + (size_t)(ct * 32 + col16) * 128 + quad * 8;
        f32x4 a00 = {0.f, 0.f, 0.f, 0.f}, a01 = a00, a10 = a00, a11 = a00;
        #pragma unroll
        for (int k0 = 0; k0 < 128; k0 += 32) {
            bf16x8 af0 = *(const bf16x8*)&xnS[(rb + col16) * 136 + k0 + quad * 8];
            bf16x8 af1 = *(const bf16x8*)&xnS[(rb + 16 + col16) * 136 + k0 + quad * 8];
            bf16x8 b0 = *(const bf16x8*)(bp + k0);
            bf16x8 b1 = *(const bf16x8*)(bp + 16 * 128 + k0);
            a00 = MFMA16(af0, b0, a00);
            a01 = MFMA16(af0, b1, a01);
            a10 = MFMA16(af1, b0, a10);
            a11 = MFMA16(af1, b1, a11);
        }
        #pragma unroll
        for (int r = 0; r < 4; ++r) {
            const int gr0 = rb + quad * 4 + r, gr1 = gr0 + 16;
            Gs[gr0 * GST + (cb + col16) * 4 + gg]      = f2bf(a00[r]);
            Gs[gr0 * GST + (cb + 16 + col16) * 4 + gg] = f2bf(a01[r]);
            Gs[gr1 * GST + (cb + col16) * 4 + gg]      = f2bf(a10[r]);
            Gs[gr1 * GST + (cb + 16 + col16) * 4 + gg] = f2bf(a11[r]);
        }
    }
    float hp[12] = {};
    __syncthreads();

    for (int t = 0; t < KWIN; ++t) {
        const int shift = KWIN - 1 - t;
        u16* wbuf = (t & 1) ? hsB : hsA;
        const u16* rbuf = (t & 1) ? hsA : hsB;
        // hoisted gate loads: one b64 per row (overlaps following MFMA issue)
        u16x4 gv[12];
        #pragma unroll
        for (int rh = 0; rh < 3; ++rh)
            #pragma unroll
            for (int r = 0; r < 4; ++r) {
                const int lrow = rh * 16 + quad * 4 + r;
                gv[rh * 4 + r] = *(const u16x4*)&Gs[(lrow - shift + 6) * GST + cc * 4];
            }
        f32x4 acc[3][3];
        #pragma unroll
        for (int rh = 0; rh < 3; ++rh)
            #pragma unroll
            for (int g = 0; g < 3; ++g) acc[rh][g] = {0.f, 0.f, 0.f, 0.f};
        if (t > 0) {
            bf16x8 af[3][4];
            #pragma unroll
            for (int rh = 0; rh < 3; ++rh)
                #pragma unroll
                for (int kc = 0; kc < 4; ++kc)
                    af[rh][kc] = *(const bf16x8*)&rbuf[(rh * 16 + col16) * 136 + kc * 32 + quad * 8];
            #pragma unroll
            for (int kc = 0; kc < 4; ++kc)
                #pragma unroll
                for (int g = 0; g < 3; ++g)
                    #pragma unroll
                    for (int rh = 0; rh < 3; ++rh)
                        acc[rh][g] = MFMA16(af[rh][kc], Breg[g][kc], acc[rh][g]);
        }
        const bool last = (t == KWIN - 1);
        #pragma unroll
        for (int rh = 0; rh < 3; ++rh) {
            #pragma unroll
            for (int r = 0; r < 4; ++r) {
                const int idx = rh * 4 + r;
                const int lrow = rh * 16 + quad * 4 + r;
                const float xr  = b2f(gv[idx][0]);
                const float xz  = b2f(gv[idx][1]);
                const float xn_ = b2f(gv[idx][2]);
                const float rr = fsigmoid(xr + bi[0] + acc[rh][0][r] + bh[0]);
                const float zz = fsigmoid(xz + bi[1] + acc[rh][1][r] + bh[1]);
                const float nn = ftanh(xn_ + bi[2] + rr * (acc[rh][2][r] + bh[2]));
                const float hnew = (1.f - zz) * nn + zz * hp[idx];
                hp[idx] = hnew;
                if (!last) wbuf[lrow * 136 + cc] = f2bf(hnew);
            }
        }
        __syncthreads();   // single barrier/step: wbuf writes visible; rbuf reads drained
    }
    // residual + ln_attn -> hsA (bf16 xna). Gs reused as f32 hf[48][132].
    float* hf = (float*)Gs;
    #pragma unroll
    for (int rh = 0; rh < 3; ++rh)
        #pragma unroll
        for (int r = 0; r < 4; ++r) {
            const int lrow = rh * 16 + quad * 4 + r;
            const float hv = hp[rh * 4 + r] + hout[(size_t)(row0 + lrow) * D + cc];
            hout[(size_t)(row0 + lrow) * D + cc] = hv;
            hf[lrow * 132 + cc] = hv;
        }
    __syncthreads();
    {
        const int r = tid >> 3;
        if (r < RB) {
            const int cg = (tid & 7) * 16;
            float vals[16];
            #pragma unroll
            for (int jj = 0; jj < 4; ++jj) {
                float4 v = *(const float4*)&hf[r * 132 + cg + 4 * jj];
                vals[4 * jj] = v.x; vals[4 * jj + 1] = v.y; vals[4 * jj + 2] = v.z; vals[4 * jj + 3] = v.w;
            }
            float s = 0.f;
            #pragma unroll
            for (int j = 0; j < 16; ++j) s += vals[j];
            s += __shfl_xor(s, 1); s += __shfl_xor(s, 2); s += __shfl_xor(s, 4);
            const float mean = s * (1.f / D);
            float q = 0.f;
            #pragma unroll
            for (int j = 0; j < 16; ++j) { float d = vals[j] - mean; q += d * d; }
            q += __shfl_xor(q, 1); q += __shfl_xor(q, 2); q += __shfl_xor(q, 4);
            const float inv = frcp(sqrtf(q * (1.f / (D - 1))) + EPS);
            #pragma unroll
            for (int jj = 0; jj < 4; ++jj) {
                u16x4 o;
                #pragma unroll
                for (int c = 0; c < 4; ++c)
                    o[c] = f2bf(ga[cg + 4 * jj + c] * (vals[4 * jj + c] - mean) * inv + gb[cg + 4 * jj + c]);
                *(u16x4*)&hsA[r * 136 + cg + 4 * jj] = o;
            }
        }
    }
    __syncthreads();
    // QKV: 36 (16x32) tiles, A from hsA (xna), B from Wqkv
    for (int tt = wave; tt < 36; tt += 8) {
        const int rt = tt / 12, ct = tt - rt * 12;
        const int seg = ct >> 2;
        const int c0 = (ct & 3) * 32;
        const u16* bp = Wqkv + (size_t)(seg * 128 + c0 + col16) * 128 + quad * 8;
        f32x4 a0 = {0.f, 0.f, 0.f, 0.f}, a1 = a0;
        #pragma unroll
        for (int k0 = 0; k0 < 128; k0 += 32) {
            bf16x8 af = *(const bf16x8*)&hsA[(rt * 16 + col16) * 136 + k0 + quad * 8];
            bf16x8 b0 = *(const bf16x8*)(bp + k0);
            bf16x8 b1 = *(const bf16x8*)(bp + 16 * 128 + k0);
            a0 = MFMA16(af, b0, a0);
            a1 = MFMA16(af, b1, a1);
        }
        if (seg < 2) {
            const float* bias = seg == 0 ? bq : bk;
            const float sc = seg == 0 ? QS : 1.f;
            const float bv0 = bias[c0 + col16], bv1 = bias[c0 + 16 + col16];
            u16* o16 = seg == 0 ? q16 : k16;
            #pragma unroll
            for (int r = 0; r < 4; ++r) {
                const size_t gr = (size_t)(row0 + rt * 16 + quad * 4 + r) * 128;
                o16[gr + c0 + col16]      = f2bf((a0[r] + bv0) * sc);
                o16[gr + c0 + 16 + col16] = f2bf((a1[r] + bv1) * sc);
            }
        } else {
            const float bv0 = bv[c0 + col16], bv1 = bv[c0 + 16 + col16];
            const int bb = row0 / S, ssv = row0 - bb * S + rt * 16;
            const int ca = c0 + col16, cb = c0 + 16 + col16;
            u16* pa = vt16 + ((size_t)((bb * NH + (ca >> 5)) * 32 + (ca & 31))) * S + ssv;
            u16* pb = vt16 + ((size_t)((bb * NH + (cb >> 5)) * 32 + (cb & 31))) * S + ssv;
            #pragma unroll
            for (int r = 0; r < 4; ++r) {
                pa[quad * 4 + r] = f2bf(a0[r] + bv0);
                pb[quad * 4 + r] = f2bf(a1[r] + bv1);
            }
        }
    }
}

// ---------------------------------------------------------------- MFMA flash attention v3
// Block = (q-tile pair (p, 47-p), bh); 32-row Q-tiles; 4 waves split the key tiles.
// No-max softmax => partials merge by ADDITION. Uniform 49 k-tiles per block.
// Q pre-scaled by scale*log2e => p = exp2(score). NOTE: O16 may alias Qb (each
// (row, col-group) has a single owning block that reads Q before writing O).
__global__ __launch_bounds__(256) void k_attn_mfma(
    const u16* Qb, const u16* __restrict__ Kb,
    const u16* __restrict__ Vt, u16* O16) {
    const int wave = threadIdx.x >> 6, lane = threadIdx.x & 63;
    const int p = blockIdx.x;        // 0..23
    const int bh = blockIdx.y;       // 0..31
    const int b = bh >> 2, hh = bh & 3;
    const int col = lane & 15, quad = lane >> 4;

    __shared__ __align__(16) u16 Pb[4][32][40];   // per-wave P tiles
    __shared__ float Om[4][32][33];               // per-wave O partials
    __shared__ float Lm[4][32];                   // per-wave l partials
    u16 (* __restrict__ P)[40] = Pb[wave];

    const u16* Kbase = Kb + (size_t)b * S * 128 + hh * 32;
    const u16* Vbase = Vt + (size_t)bh * 32 * S;

    #pragma unroll
    for (int half = 0; half < 2; ++half) {
        const int qt = half == 0 ? p : 47 - p;
        const int q0 = qt * 32;
        const int nkt = qt + 1;
        const u16* qp = Qb + (size_t)(b * S + q0 + col) * 128 + hh * 32 + quad * 8;
        const bf16x8 qf0 = *(const bf16x8*)qp;
        const bf16x8 qf1 = *(const bf16x8*)(qp + 16 * 128);
        f32x4 o00 = {0.f, 0.f, 0.f, 0.f}, o01 = o00, o10 = o00, o11 = o00;
        float lsum[8] = {};
        int kt = wave;
        bf16x8 kf0 = {}, kf1 = {}, vf0 = {}, vf1 = {};
        if (kt < nkt) {
            const u16* kp = Kbase + (size_t)(kt * 32 + col) * 128 + quad * 8;
            kf0 = *(const bf16x8*)kp;
            kf1 = *(const bf16x8*)(kp + 16 * 128);
            const u16* vp = Vbase + (size_t)col * S + kt * 32 + quad * 8;
            vf0 = *(const bf16x8*)vp;
            vf1 = *(const bf16x8*)(vp + 16 * S);
        }
        while (kt < nkt) {
            const int ktn = kt + 4;
            bf16x8 nk0 = kf0, nk1 = kf1, nv0 = vf0, nv1 = vf1;
            if (ktn < nkt) {   // prefetch next K/V tile
                const u16* kp = Kbase + (size_t)(ktn * 32 + col) * 128 + quad * 8;
                nk0 = *(const bf16x8*)kp;
                nk1 = *(const bf16x8*)(kp + 16 * 128);
                const u16* vp = Vbase + (size_t)col * S + ktn * 32 + quad * 8;
                nv0 = *(const bf16x8*)vp;
                nv1 = *(const bf16x8*)(vp + 16 * S);
            }
            f32x4 z = {0.f, 0.f, 0.f, 0.f};
            f32x4 s00 = MFMA16(qf0, kf0, z);
            f32x4 s01 = MFMA16(qf0, kf1, z);
            f32x4 s10 = MFMA16(qf1, kf0, z);
            f32x4 s11 = MFMA16(qf1, kf1, z);
            const bool diag = (kt == qt);
            const int k0g = kt * 32;
            #pragma unroll
            for (int r = 0; r < 4; ++r) {
                const int lr = quad * 4 + r;
                float p00 = fexp2(s00[r]);
                float p01 = fexp2(s01[r]);
                float p10 = fexp2(s10[r]);
                float p11 = fexp2(s11[r]);
                if (diag) {
                    const int qg0 = q0 + lr, qg1 = q0 + 16 + lr;
                    if (k0g + col > qg0)      p00 = 0.f;
                    if (k0g + 16 + col > qg0) p01 = 0.f;
                    if (k0g + col > qg1)      p10 = 0.f;
                    if (k0g + 16 + col > qg1) p11 = 0.f;
                }
                lsum[r]     += p00 + p01;
                lsum[4 + r] += p10 + p11;
                P[lr][col]           = f2bf(p00);
                P[lr][16 + col]      = f2bf(p01);
                P[16 + lr][col]      = f2bf(p10);
                P[16 + lr][16 + col] = f2bf(p11);
            }
            const bf16x8 pa0 = *(const bf16x8*)&P[col][quad * 8];
            const bf16x8 pa1 = *(const bf16x8*)&P[16 + col][quad * 8];
            o00 = MFMA16(pa0, vf0, o00);
            o01 = MFMA16(pa0, vf1, o01);
            o10 = MFMA16(pa1, vf0, o10);
            o11 = MFMA16(pa1, vf1, o11);
            kf0 = nk0; kf1 = nk1; vf0 = nv0; vf1 = nv1;
            kt = ktn;
        }
        #pragma unroll
        for (int i = 0; i < 8; ++i) {
            float v = lsum[i];
            v += __shfl_xor(v, 1); v += __shfl_xor(v, 2);
            v += __shfl_xor(v, 4); v += __shfl_xor(v, 8);
            lsum[i] = v;
        }
        #pragma unroll
        for (int r = 0; r < 4; ++r) {
            const int lr = quad * 4 + r;
            Om[wave][lr][col]           = o00[r];
            Om[wave][lr][16 + col]      = o01[r];
            Om[wave][16 + lr][col]      = o10[r];
            Om[wave][16 + lr][16 + col] = o11[r];
        }
        if (col == 0) {
            #pragma unroll
            for (int i = 0; i < 8; ++i)
                Lm[wave][(i >> 2) * 16 + quad * 4 + (i & 3)] = lsum[i];
        }
        __syncthreads();
        {
            const int tr = threadIdx.x >> 3, tc = (threadIdx.x & 7) * 4;
            const float inv = frcp(Lm[0][tr] + Lm[1][tr] + Lm[2][tr] + Lm[3][tr]);
            u16x4 outv;
            #pragma unroll
            for (int c = 0; c < 4; ++c) {
                const float o = Om[0][tr][tc + c] + Om[1][tr][tc + c] +
                                Om[2][tr][tc + c] + Om[3][tr][tc + c];
                outv[c] = f2bf(o * inv);
            }
            *(u16x4*)(O16 + (size_t)(b * S + q0 + tr) * 128 + hh * 32 + tc) = outv;
        }
        __syncthreads();   // Om/Lm/Pb reused by the second half
    }
}

// ---------------------------------------------------------------- merged Wo + FFN (32-row blocks)
// Block owns 32 FULL rows. h += ao@Wo^T + bo; ln_ff -> LDS; FF1(relu) -> LDS;
// FF2; h += ; then LAST ? sigmoid head : ln_rnn(next) -> xnout.
template <bool LAST>
__global__ __launch_bounds__(256) void k_mho_ffn(
    const u16* __restrict__ ao, const u16* __restrict__ WoT, const float* __restrict__ bo,
    float* __restrict__ hio,
    const float* __restrict__ ga1, const float* __restrict__ gb1,
    const u16* __restrict__ W1T, const float* __restrict__ b1,
    const u16* __restrict__ W2T, const float* __restrict__ b2,
    const float* __restrict__ ga2, const float* __restrict__ gb2, u16* __restrict__ xnout,
    const float* __restrict__ outW, const float* __restrict__ outb, float* __restrict__ outp) {
    __shared__ float hL[32 * 132];              // 16896 B (persists)
    __shared__ __align__(16) u16 xnL[32 * 136]; // 8704 B (ln_ff out)
    __shared__ __align__(16) u16 Ls[32 * 520];  // 33280 B (ff1 out)
    const int tid = threadIdx.x;
    const int wave = tid >> 6, lane = tid & 63;
    const int col16 = lane & 15, quad = lane >> 4;
    const int row0 = blockIdx.x * 32;
    const int c0 = wave * 32;

    // Wo GEMM (K=128)
    {
        const u16* a0p = ao + (size_t)(row0 + col16) * 128 + quad * 8;
        const u16* b0p = WoT + (size_t)(c0 + col16) * 128 + quad * 8;
        f32x4 acc00 = {0.f, 0.f, 0.f, 0.f}, acc01 = acc00, acc10 = acc00, acc11 = acc00;
        mfma_tile32<128>(a0p, a0p + 16 * 128, b0p, b0p + 16 * 128, acc00, acc01, acc10, acc11);
        const float bv0 = bo[c0 + col16];
        const float bv1 = bo[c0 + 16 + col16];
        #pragma unroll
        for (int r = 0; r < 4; ++r) {
            const int l0 = quad * 4 + r, l1 = 16 + quad * 4 + r;
            const size_t g0 = (size_t)(row0 + l0) * D, g1 = (size_t)(row0 + l1) * D;
            hL[l0 * 132 + c0 + col16]      = acc00[r] + bv0 + hio[g0 + c0 + col16];
            hL[l0 * 132 + c0 + 16 + col16] = acc01[r] + bv1 + hio[g0 + c0 + 16 + col16];
            hL[l1 * 132 + c0 + col16]      = acc10[r] + bv0 + hio[g1 + c0 + col16];
            hL[l1 * 132 + c0 + 16 + col16] = acc11[r] + bv1 + hio[g1 + c0 + 16 + col16];
        }
    }
    __syncthreads();
    // ln_ff -> xnL (bf16)
    {
        const int r = tid >> 3, cg = (tid & 7) * 16;
        float vals[16];
        #pragma unroll
        for (int jj = 0; jj < 4; ++jj) {
            float4 v = *(const float4*)&hL[r * 132 + cg + 4 * jj];
            vals[4 * jj] = v.x; vals[4 * jj + 1] = v.y; vals[4 * jj + 2] = v.z; vals[4 * jj + 3] = v.w;
        }
        float s = 0.f;
        #pragma unroll
        for (int j = 0; j < 16; ++j) s += vals[j];
        s += __shfl_xor(s, 1); s += __shfl_xor(s, 2); s += __shfl_xor(s, 4);
        const float mean = s * (1.f / D);
        float q = 0.f;
        #pragma unroll
        for (int j = 0; j < 16; ++j) { float d = vals[j] - mean; q += d * d; }
        q += __shfl_xor(q, 1); q += __shfl_xor(q, 2); q += __shfl_xor(q, 4);
        const float inv = frcp(sqrtf(q * (1.f / (D - 1))) + EPS);
        #pragma unroll
        for (int jj = 0; jj < 4; ++jj) {
            u16x4 o;
            #pragma unroll
            for (int c = 0; c < 4; ++c)
                o[c] = f2bf(ga1[cg + 4 * jj + c] * (vals[4 * jj + c] - mean) * inv + gb1[cg + 4 * jj + c]);
            *(u16x4*)&xnL[r * 136 + cg + 4 * jj] = o;
        }
    }
    __syncthreads();
    // FF1: wave computes cols [wave*128, +128), A from xnL
    #pragma unroll
    for (int ct = 0; ct < 4; ++ct) {
        const int c0f = wave * 128 + ct * 32;
        const u16* b0p = W1T + (size_t)(c0f + col16) * 128 + quad * 8;
        f32x4 acc00 = {0.f, 0.f, 0.f, 0.f}, acc01 = acc00, acc10 = acc00, acc11 = acc00;
        #pragma unroll
        for (int k0 = 0; k0 < 128; k0 += 32) {
            bf16x8 a0 = *(const bf16x8*)&xnL[col16 * 136 + k0 + quad * 8];
            bf16x8 a1 = *(const bf16x8*)&xnL[(16 + col16) * 136 + k0 + quad * 8];
            bf16x8 b0 = *(const bf16x8*)(b0p + k0);
            bf16x8 b1 = *(const bf16x8*)(b0p + 16 * 128 + k0);
            acc00 = MFMA16(a0, b0, acc00);
            acc01 = MFMA16(a0, b1, acc01);
            acc10 = MFMA16(a1, b0, acc10);
            acc11 = MFMA16(a1, b1, acc11);
        }
        const float bv0 = b1[c0f + col16];
        const float bv1 = b1[c0f + 16 + col16];
        #pragma unroll
        for (int r = 0; r < 4; ++r) {
            const int l0 = quad * 4 + r, l1 = 16 + quad * 4 + r;
            Ls[l0 * 520 + c0f + col16]      = f2bf(fmaxf(acc00[r] + bv0, 0.f));
            Ls[l0 * 520 + c0f + 16 + col16] = f2bf(fmaxf(acc01[r] + bv1, 0.f));
            Ls[l1 * 520 + c0f + col16]      = f2bf(fmaxf(acc10[r] + bv0, 0.f));
            Ls[l1 * 520 + c0f + 16 + col16] = f2bf(fmaxf(acc11[r] + bv1, 0.f));
        }
    }
    __syncthreads();
    // FF2: wave computes out cols [wave*32, +32), K=512 from Ls
    {
        f32x4 acc00 = {0.f, 0.f, 0.f, 0.f}, acc01 = acc00, acc10 = acc00, acc11 = acc00;
        #pragma unroll
        for (int k0 = 0; k0 < 512; k0 += 32) {
            bf16x8 a0 = *(const bf16x8*)&Ls[col16 * 520 + k0 + quad * 8];
            bf16x8 a1 = *(const bf16x8*)&Ls[(16 + col16) * 520 + k0 + quad * 8];
            const u16* bp = W2T + (size_t)(c0 + col16) * 512 + k0 + quad * 8;
            bf16x8 b0 = *(const bf16x8*)bp;
            bf16x8 b1v = *(const bf16x8*)(bp + 16 * 512);
            acc00 = MFMA16(a0, b0, acc00);
            acc01 = MFMA16(a0, b1v, acc01);
            acc10 = MFMA16(a1, b0, acc10);
            acc11 = MFMA16(a1, b1v, acc11);
        }
        const float bv0 = b2[c0 + col16];
        const float bv1 = b2[c0 + 16 + col16];
        #pragma unroll
        for (int r = 0; r < 4; ++r) {
            const int l0 = quad * 4 + r, l1 = 16 + quad * 4 + r;
            const size_t g0 = (size_t)(row0 + l0) * D, g1 = (size_t)(row0 + l1) * D;
            const float v00 = acc00[r] + bv0 + hL[l0 * 132 + c0 + col16];
            const float v01 = acc01[r] + bv1 + hL[l0 * 132 + c0 + 16 + col16];
            const float v10 = acc10[r] + bv0 + hL[l1 * 132 + c0 + col16];
            const float v11 = acc11[r] + bv1 + hL[l1 * 132 + c0 + 16 + col16];
            hio[g0 + c0 + col16]      = v00;
            hio[g0 + c0 + 16 + col16] = v01;
            hio[g1 + c0 + col16]      = v10;
            hio[g1 + c0 + 16 + col16] = v11;
            hL[l0 * 132 + c0 + col16]      = v00;
            hL[l0 * 132 + c0 + 16 + col16] = v01;
            hL[l1 * 132 + c0 + col16]      = v10;
            hL[l1 * 132 + c0 + 16 + col16] = v11;
        }
    }
    __syncthreads();
    // tail
    {
        const int r = tid >> 3, cg = (tid & 7) * 16;
        float vals[16];
        #pragma unroll
        for (int jj = 0; jj < 4; ++jj) {
            float4 v = *(const float4*)&hL[r * 132 + cg + 4 * jj];
            vals[4 * jj] = v.x; vals[4 * jj + 1] = v.y; vals[4 * jj + 2] = v.z; vals[4 * jj + 3] = v.w;
        }
        if constexpr (LAST) {
            float dot = 0.f;
            #pragma unroll
            for (int j = 0; j < 16; ++j) dot += vals[j] * outW[cg + j];
            dot += __shfl_xor(dot, 1); dot += __shfl_xor(dot, 2); dot += __shfl_xor(dot, 4);
            if ((tid & 7) == 0) outp[row0 + r] = sigmoidf_(dot + outb[0]);
        } else {
            float s = 0.f;
            #pragma unroll
            for (int j = 0; j < 16; ++j) s += vals[j];
            s += __shfl_xor(s, 1); s += __shfl_xor(s, 2); s += __shfl_xor(s, 4);
            const float mean = s * (1.f / D);
            float q = 0.f;
            #pragma unroll
            for (int j = 0; j < 16; ++j) { float d = vals[j] - mean; q += d * d; }
            q += __shfl_xor(q, 1); q += __shfl_xor(q, 2); q += __shfl_xor(q, 4);
            const float inv = frcp(sqrtf(q * (1.f / (D - 1))) + EPS);
            u16* xp = xnout + (size_t)(row0 + r) * D + cg;
            #pragma unroll
            for (int jj = 0; jj < 4; ++jj) {
                u16x4 o;
                #pragma unroll
                for (int c = 0; c < 4; ++c)
                    o[c] = f2bf(ga2[cg + 4 * jj + c] * (vals[4 * jj + c] - mean) * inv + gb2[cg + 4 * jj + c]);
                *(u16x4*)(xp + 4 * jj) = o;
            }
        }
    }
}

// ---------------------------------------------------------------- host
extern "C" void kernel_launch(void* const* d_in, const int* in_sizes, int n_in,
                              void* d_out, int out_size, void* d_ws, size_t ws_size,
                              hipStream_t stream) {
    const float* x       = (const float*)d_in[0];
    const float* enc_W   = (const float*)d_in[1];
    const float* enc_b   = (const float*)d_in[2];
    const float* ln_rnn_a = (const float*)d_in[3];
    const float* ln_rnn_b = (const float*)d_in[4];
    const float* gru_Wih = (const float*)d_in[5];
    const float* gru_Whh = (const float*)d_in[6];
    const float* gru_bih = (const float*)d_in[7];
    const float* gru_bhh = (const float*)d_in[8];
    const float* ln_attn_a = (const float*)d_in[9];
    const float* ln_attn_b = (const float*)d_in[10];
    const float* Wq = (const float*)d_in[11];
    const float* bq = (const float*)d_in[12];
    const float* Wk = (const float*)d_in[13];
    const float* bk = (const float*)d_in[14];
    const float* Wv = (const float*)d_in[15];
    const float* bv = (const float*)d_in[16];
    const float* Wo = (const float*)d_in[17];
    const float* bo = (const float*)d_in[18];
    const float* ln_ff_a = (const float*)d_in[19];
    const float* ln_ff_b = (const float*)d_in[20];
    const float* ff_W1 = (const float*)d_in[21];
    const float* ff_b1 = (const float*)d_in[22];
    const float* ff_W2 = (const float*)d_in[23];
    const float* ff_b2 = (const float*)d_in[24];
    const float* out_W = (const float*)d_in[25];
    const float* out_b = (const float*)d_in[26];

    float* h   = (float*)d_ws;                 // MD f32
    u16* pool  = (u16*)(h + MD);               // 3*MD u16 (q|k|vt)
    u16* xn16  = pool + (size_t)3 * MD;        // MD u16 (ln_rnn outputs)
    u16* Wih16 = xn16 + MD;
    u16* Whh16 = Wih16 + NLVL * 384 * D;
    u16* Wqkv  = Whh16 + NLVL * 384 * D;       // [lvl][384][128]
    u16* WoT   = Wqkv + NLVL * 384 * D;
    u16* W1T   = WoT + NLVL * D * D;           // [lvl][512][128]
    u16* W2T   = W1T + NLVL * D * DFF;         // [lvl][128][512]

    u16* q16   = pool;                         // Q; attention output overwrites it
    u16* k16   = pool + MD;
    u16* vt16  = pool + (size_t)2 * MD;
    u16* ao16  = q16;                          // attention output (aliases Q; safe)

    k_prep_enc<<<2688, 256, 0, stream>>>(
        gru_Wih, gru_Whh, Wq, Wk, Wv, Wo, ff_W1, ff_W2,
        Wih16, Whh16, Wqkv, WoT, W1T, W2T,
        x, enc_W, enc_b, ln_rnn_a, ln_rnn_b, h, xn16);

    for (int lvl = 0; lvl < NLVL; ++lvl) {
        // --- LocalRNN + ln_attn + QKV (one kernel; 256 blocks x 48 rows, 2 blocks/CU) ---
        k_gru_qkv<<<M / 48, 512, 0, stream>>>(
            xn16, Wih16 + lvl * 384 * D, Whh16 + lvl * 384 * D,
            gru_bih + lvl * 384, gru_bhh + lvl * 384,
            h, ln_attn_a + lvl * D, ln_attn_b + lvl * D,
            Wqkv + lvl * 384 * D, bq + lvl * D, bk + lvl * D, bv + lvl * D,
            q16, k16, vt16);

        // --- attention ---
        k_attn_mfma<<<dim3(24, 32), 256, 0, stream>>>(q16, k16, vt16, ao16);

        // --- Wo + FFN merged (fuses next ln_rnn or the output head) ---
        if (lvl + 1 < NLVL) {
            k_mho_ffn<false><<<M / 32, 256, 0, stream>>>(
                ao16, WoT + lvl * D * D, bo + lvl * D, h,
                ln_ff_a + lvl * D, ln_ff_b + lvl * D,
                W1T + lvl * D * DFF, ff_b1 + lvl * DFF,
                W2T + lvl * DFF * D, ff_b2 + lvl * D,
                ln_rnn_a + (lvl + 1) * D, ln_rnn_b + (lvl + 1) * D, xn16,
                nullptr, nullptr, nullptr);
        } else {
            k_mho_ffn<true><<<M / 32, 256, 0, stream>>>(
                ao16, WoT + lvl * D * D, bo + lvl * D, h,
                ln_ff_a + lvl * D, ln_ff_b + lvl * D,
                W1T + lvl * D * DFF, ff_b1 + lvl * DFF,
                W2T + lvl * DFF * D, ff_b2 + lvl * D,
                nullptr, nullptr, nullptr,
                out_W, out_b, (float*)d_out);
        }
    }
}

// Round 13
// 291.134 us; speedup vs baseline: 1.0081x; 1.0081x over previous
//
#include <hip/hip_runtime.h>
#include <math.h>

#define DEV_INLINE __device__ __forceinline__

constexpr int B = 8, S = 1536, IN = 32, D = 128, NH = 4, KWIN = 7, NLVL = 2;
constexpr int DFF = 512, DKH = 32;
constexpr int M = B * S;           // 12288 rows
constexpr int MD = M * D;          // 1572864
constexpr float EPS = 1e-6f;
constexpr float LOG2E = 1.4426950408889634f;

typedef unsigned short u16;
typedef __bf16 bf16x8 __attribute__((ext_vector_type(8)));
typedef float f32x4 __attribute__((ext_vector_type(4)));
typedef unsigned short u16x4 __attribute__((ext_vector_type(4)));

#define MFMA16(a, b, c) __builtin_amdgcn_mfma_f32_16x16x32_bf16(a, b, c, 0, 0, 0)

DEV_INLINE float frcp(float x) { return __builtin_amdgcn_rcpf(x); }
DEV_INLINE float fexp2(float x) { return __builtin_amdgcn_exp2f(x); }
DEV_INLINE float sigmoidf_(float x) { return 1.f / (1.f + __expf(-x)); }
// fast sigmoid/tanh: rcp+exp2 (error ~1e-7 rel, far below bf16 rounding)
DEV_INLINE float fsigmoid(float x) { return frcp(1.f + fexp2(-LOG2E * x)); }
DEV_INLINE float ftanh(float x) { return 1.f - 2.f * frcp(fexp2(2.f * LOG2E * x) + 1.f); }

DEV_INLINE u16 f2bf(float f) {
    unsigned u = __builtin_bit_cast(unsigned, f);
    unsigned rnd = 0x7FFFu + ((u >> 16) & 1u);
    return (u16)((u + rnd) >> 16);
}
DEV_INLINE float b2f(u16 v) { return __builtin_bit_cast(float, (unsigned)v << 16); }

// shared 32x32-tile K-loop (A rows / Bt rows both [.][KDIM] bf16, global)
template <int KDIM>
DEV_INLINE void mfma_tile32(const u16* a0p, const u16* a1p, const u16* b0p, const u16* b1p,
                            f32x4& acc00, f32x4& acc01, f32x4& acc10, f32x4& acc11) {
    #pragma unroll
    for (int k0 = 0; k0 < KDIM; k0 += 32) {
        bf16x8 a0 = *(const bf16x8*)(a0p + k0);
        bf16x8 a1 = *(const bf16x8*)(a1p + k0);
        bf16x8 b0 = *(const bf16x8*)(b0p + k0);
        bf16x8 b1 = *(const bf16x8*)(b1p + k0);
        acc00 = MFMA16(a0, b0, acc00);
        acc01 = MFMA16(a0, b1, acc01);
        acc10 = MFMA16(a1, b0, acc10);
        acc11 = MFMA16(a1, b1, acc11);
    }
}

// ---------------------------------------------------------------- weight prep + encoder (merged)
__global__ __launch_bounds__(256) void k_prep_enc(
    const float* __restrict__ Wih, const float* __restrict__ Whh,
    const float* __restrict__ Wq, const float* __restrict__ Wk,
    const float* __restrict__ Wv, const float* __restrict__ Wo,
    const float* __restrict__ W1, const float* __restrict__ W2,
    u16* __restrict__ Wih16, u16* __restrict__ Whh16,
    u16* __restrict__ Wqkv, u16* __restrict__ WoT,
    u16* __restrict__ W1T, u16* __restrict__ W2T,
    const float* __restrict__ x, const float* __restrict__ encW, const float* __restrict__ encb,
    const float* __restrict__ ga, const float* __restrict__ gb,
    float* __restrict__ h, u16* __restrict__ xnout) {
    __shared__ float xs[32][33];
    __shared__ float Ws[32][128];
    const int tid = threadIdx.x;
    if (blockIdx.x < 2304) {
        constexpr int SZ_GRU = NLVL * 384 * 128;   // 98304
        constexpr int SZ_DD  = NLVL * 128 * 128;   // 32768
        constexpr int SZ_FF  = NLVL * 128 * 512;   // 131072
        int i = blockIdx.x * 256 + tid;
        if (i < SZ_GRU) { Wih16[i] = f2bf(Wih[i]); return; }
        i -= SZ_GRU;
        if (i < SZ_GRU) { Whh16[i] = f2bf(Whh[i]); return; }
        i -= SZ_GRU;
        if (i < 3 * SZ_DD) {  // Wq/Wk/Wv [lvl][k][n] -> Wqkv[lvl][seg*128+n][k]
            int seg = i / SZ_DD, j = i - seg * SZ_DD;
            int lvl = j >> 14, rem = j & 16383, k = rem >> 7, n = rem & 127;
            const float* src = seg == 0 ? Wq : (seg == 1 ? Wk : Wv);
            Wqkv[(size_t)lvl * 384 * 128 + (size_t)(seg * 128 + n) * 128 + k] = f2bf(src[j]);
            return;
        }
        i -= 3 * SZ_DD;
        if (i < SZ_DD) {      // Wo [lvl][k][n] -> [lvl][n][k]
            int lvl = i >> 14, rem = i & 16383, k = rem >> 7, n = rem & 127;
            WoT[(size_t)lvl * 16384 + n * 128 + k] = f2bf(Wo[i]); return;
        }
        i -= SZ_DD;
        if (i < SZ_FF) {      // W1 [lvl][k<128][n<512] -> [lvl][n][k]
            int lvl = i >> 16, rem = i & 65535, k = rem >> 9, n = rem & 511;
            W1T[(size_t)lvl * 65536 + n * 128 + k] = f2bf(W1[i]); return;
        }
        i -= SZ_FF;
        if (i < SZ_FF) {      // W2 [lvl][k<512][n<128] -> [lvl][n][k]
            int lvl = i >> 16, rem = i & 65535, k = rem >> 7, n = rem & 127;
            W2T[(size_t)lvl * 65536 + n * 512 + k] = f2bf(W2[i]); return;
        }
        return;
    }
    // ---- encoder path ----
    const int row0 = (blockIdx.x - 2304) * 32;
    for (int i = tid; i < 32 * 32; i += 256) xs[i >> 5][i & 31] = x[(size_t)row0 * IN + i];
    for (int i = tid; i < 32 * 128; i += 256) Ws[i >> 7][i & 127] = encW[i];
    __syncthreads();
    const int r = tid >> 3, cg = (tid & 7) * 16;
    float acc[16];
    #pragma unroll
    for (int j = 0; j < 16; ++j) acc[j] = encb[cg + j];
    for (int k = 0; k < IN; ++k) {
        const float xv = xs[r][k];
        #pragma unroll
        for (int j = 0; j < 16; ++j) acc[j] = fmaf(xv, Ws[k][cg + j], acc[j]);
    }
    float s = 0.f;
    #pragma unroll
    for (int j = 0; j < 16; ++j) s += acc[j];
    s += __shfl_xor(s, 1); s += __shfl_xor(s, 2); s += __shfl_xor(s, 4);
    const float mean = s * (1.f / D);
    float q = 0.f;
    #pragma unroll
    for (int j = 0; j < 16; ++j) { float d = acc[j] - mean; q += d * d; }
    q += __shfl_xor(q, 1); q += __shfl_xor(q, 2); q += __shfl_xor(q, 4);
    const float inv = 1.f / (sqrtf(q * (1.f / (D - 1))) + EPS);
    float* hp = h + (size_t)(row0 + r) * D + cg;
    u16* xp = xnout + (size_t)(row0 + r) * D + cg;
    #pragma unroll
    for (int jj = 0; jj < 4; ++jj) {
        float4 hv = make_float4(acc[4 * jj], acc[4 * jj + 1], acc[4 * jj + 2], acc[4 * jj + 3]);
        *(float4*)(hp + 4 * jj) = hv;
        u16x4 o;
        #pragma unroll
        for (int c = 0; c < 4; ++c)
            o[c] = f2bf(ga[cg + 4 * jj + c] * (acc[4 * jj + c] - mean) * inv + gb[cg + 4 * jj + c]);
        *(u16x4*)(xp + 4 * jj) = o;
    }
}

// ---------------------------------------------------------------- fused windowed GRU + ln_attn + QKV
// 256 blocks x 512 thr; LDS pooled to 81840 B so TWO blocks fit per CU.
__global__ __launch_bounds__(512, 2) void k_gru_qkv(
    const u16* __restrict__ xn,     // [M][128] bf16 ln_rnn output
    const u16* __restrict__ Wih16,  // [384][128] bf16
    const u16* __restrict__ Whh16,  // [384][128] bf16
    const float* __restrict__ bih, const float* __restrict__ bhh,
    float* __restrict__ hout,       // [M][128] f32 residual (read+write)
    const float* __restrict__ ga, const float* __restrict__ gb,
    const u16* __restrict__ Wqkv,   // [384][128] bf16 (Q|K|V rows)
    const float* __restrict__ bq, const float* __restrict__ bk, const float* __restrict__ bv,
    u16* __restrict__ q16, u16* __restrict__ k16, u16* __restrict__ vt16) {
    constexpr int RB = 48;
    constexpr int GST = 516;                       // Gs stride in u16 (8B-aligned rows)
    constexpr float QS = 0.17677669529663687f * 1.4426950408889634f;  // scale * log2(e)
    __shared__ __align__(16) u16 poolS[54 * GST + 2 * RB * 136];   // 81840 B total
    u16* const Gs  = poolS;                        // 54*516 u16 (55728 B); tail: f32 hf[48][132]
    u16* const hsA = poolS + 54 * GST;             // 48*136 u16
    u16* const hsB = hsA + RB * 136;               // 48*136 u16
    u16* const xnS = hsA;                          // alias: 54*136 u16 spans hsA+prefix of hsB
    const int tid = threadIdx.x;
    const int wave = tid >> 6, lane = tid & 63;
    const int col16 = lane & 15, quad = lane >> 4;
    const int row0 = blockIdx.x * RB;
    const int ss0 = row0 % S;
    const int cc = wave * 16 + col16;      // this thread's h column

    // stage xn rows row0-6 .. row0+47 (54 rows; zero pad before sequence start)
    for (int i = tid; i < 54 * 16; i += 512) {
        const int r = i >> 4, c8 = (i & 15) * 8;
        bf16x8 val = {};
        if (ss0 - 6 + r >= 0)
            val = *(const bf16x8*)(xn + (size_t)(row0 - 6 + r) * 128 + c8);
        *(bf16x8*)&xnS[r * 136 + c8] = val;
    }
    // loop-invariant Whh B-fragments + biases
    bf16x8 Breg[3][4];
    #pragma unroll
    for (int g = 0; g < 3; ++g)
        #pragma unroll
        for (int kc = 0; kc < 4; ++kc)
            Breg[g][kc] = *(const bf16x8*)(Whh16 + (size_t)(g * 128 + cc) * 128 + kc * 32 + quad * 8);
    float bi[3], bh[3];
    #pragma unroll
    for (int g = 0; g < 3; ++g) { bi[g] = bih[g * 128 + cc]; bh[g] = bhh[g * 128 + cc]; }
    __syncthreads();

    // G = xn @ Wih^T : 24 tiles (2 bands x 12 col-tiles); band rows: band*22 .. band*22+31
    #pragma unroll
    for (int tt = wave; tt < 24; tt += 8) {
        const int rt = tt / 12, ct = tt - rt * 12;
        const int gg = ct >> 2;                 // gate index 0..2
        const int cb = (ct & 3) * 32;           // col base within 128
        const int rb = rt * 22;                 // band row base in Gs/xnS
        const u16* bp = Wih16 + (size_t)(ct * 32 + col16) * 128 + quad * 8;
        f32x4 a00 = {0.f, 0.f, 0.f, 0.f}, a01 = a00, a10 = a00, a11 = a00;
        #pragma unroll
        for (int k0 = 0; k0 < 128; k0 += 32) {
            bf16x8 af0 = *(const bf16x8*)&xnS[(rb + col16) * 136 + k0 + quad * 8];
            bf16x8 af1 = *(const bf16x8*)&xnS[(rb + 16 + col16) * 136 + k0 + quad * 8];
            bf16x8 b0 = *(const bf16x8*)(bp + k0);
            bf16x8 b1 = *(const bf16x8*)(bp + 16 * 128 + k0);
            a00 = MFMA16(af0, b0, a00);
            a01 = MFMA16(af0, b1, a01);
            a10 = MFMA16(af1, b0, a10);
            a11 = MFMA16(af1, b1, a11);
        }
        #pragma unroll
        for (int r = 0; r < 4; ++r) {
            const int gr0 = rb + quad * 4 + r, gr1 = gr0 + 16;
            Gs[gr0 * GST + (cb + col16) * 4 + gg]      = f2bf(a00[r]);
            Gs[gr0 * GST + (cb + 16 + col16) * 4 + gg] = f2bf(a01[r]);
            Gs[gr1 * GST + (cb + col16) * 4 + gg]      = f2bf(a10[r]);
            Gs[gr1 * GST + (cb + 16 + col16) * 4 + gg] = f2bf(a11[r]);
        }
    }
    float hp[12] = {};
    __syncthreads();

    for (int t = 0; t < KWIN; ++t) {
        const int shift = KWIN - 1 - t;
        u16* wbuf = (t & 1) ? hsB : hsA;
        const u16* rbuf = (t & 1) ? hsA : hsB;
        // hoisted gate loads: one b64 per row (overlaps following MFMA issue)
        u16x4 gv[12];
        #pragma unroll
        for (int rh = 0; rh < 3; ++rh)
            #pragma unroll
            for (int r = 0; r < 4; ++r) {
                const int lrow = rh * 16 + quad * 4 + r;
                gv[rh * 4 + r] = *(const u16x4*)&Gs[(lrow - shift + 6) * GST + cc * 4];
            }
        f32x4 acc[3][3];
        #pragma unroll
        for (int rh = 0; rh < 3; ++rh)
            #pragma unroll
            for (int g = 0; g < 3; ++g) acc[rh][g] = {0.f, 0.f, 0.f, 0.f};
        if (t > 0) {
            bf16x8 af[3][4];
            #pragma unroll
            for (int rh = 0; rh < 3; ++rh)
                #pragma unroll
                for (int kc = 0; kc < 4; ++kc)
                    af[rh][kc] = *(const bf16x8*)&rbuf[(rh * 16 + col16) * 136 + kc * 32 + quad * 8];
            #pragma unroll
            for (int kc = 0; kc < 4; ++kc)
                #pragma unroll
                for (int g = 0; g < 3; ++g)
                    #pragma unroll
                    for (int rh = 0; rh < 3; ++rh)
                        acc[rh][g] = MFMA16(af[rh][kc], Breg[g][kc], acc[rh][g]);
        }
        const bool last = (t == KWIN - 1);
        #pragma unroll
        for (int rh = 0; rh < 3; ++rh) {
            #pragma unroll
            for (int r = 0; r < 4; ++r) {
                const int idx = rh * 4 + r;
                const int lrow = rh * 16 + quad * 4 + r;
                const float xr  = b2f(gv[idx][0]);
                const float xz  = b2f(gv[idx][1]);
                const float xn_ = b2f(gv[idx][2]);
                const float rr = fsigmoid(xr + bi[0] + acc[rh][0][r] + bh[0]);
                const float zz = fsigmoid(xz + bi[1] + acc[rh][1][r] + bh[1]);
                const float nn = ftanh(xn_ + bi[2] + rr * (acc[rh][2][r] + bh[2]));
                const float hnew = (1.f - zz) * nn + zz * hp[idx];
                hp[idx] = hnew;
                if (!last) wbuf[lrow * 136 + cc] = f2bf(hnew);
            }
        }
        __syncthreads();   // single barrier/step: wbuf writes visible; rbuf reads drained
    }
    // residual + ln_attn -> hsA (bf16 xna). Gs reused as f32 hf[48][132].
    float* hf = (float*)Gs;
    #pragma unroll
    for (int rh = 0; rh < 3; ++rh)
        #pragma unroll
        for (int r = 0; r < 4; ++r) {
            const int lrow = rh * 16 + quad * 4 + r;
            const float hv = hp[rh * 4 + r] + hout[(size_t)(row0 + lrow) * D + cc];
            hout[(size_t)(row0 + lrow) * D + cc] = hv;
            hf[lrow * 132 + cc] = hv;
        }
    __syncthreads();
    {
        const int r = tid >> 3;
        if (r < RB) {
            const int cg = (tid & 7) * 16;
            float vals[16];
            #pragma unroll
            for (int jj = 0; jj < 4; ++jj) {
                float4 v = *(const float4*)&hf[r * 132 + cg + 4 * jj];
                vals[4 * jj] = v.x; vals[4 * jj + 1] = v.y; vals[4 * jj + 2] = v.z; vals[4 * jj + 3] = v.w;
            }
            float s = 0.f;
            #pragma unroll
            for (int j = 0; j < 16; ++j) s += vals[j];
            s += __shfl_xor(s, 1); s += __shfl_xor(s, 2); s += __shfl_xor(s, 4);
            const float mean = s * (1.f / D);
            float q = 0.f;
            #pragma unroll
            for (int j = 0; j < 16; ++j) { float d = vals[j] - mean; q += d * d; }
            q += __shfl_xor(q, 1); q += __shfl_xor(q, 2); q += __shfl_xor(q, 4);
            const float inv = frcp(sqrtf(q * (1.f / (D - 1))) + EPS);
            #pragma unroll
            for (int jj = 0; jj < 4; ++jj) {
                u16x4 o;
                #pragma unroll
                for (int c = 0; c < 4; ++c)
                    o[c] = f2bf(ga[cg + 4 * jj + c] * (vals[4 * jj + c] - mean) * inv + gb[cg + 4 * jj + c]);
                *(u16x4*)&hsA[r * 136 + cg + 4 * jj] = o;
            }
        }
    }
    __syncthreads();
    // QKV: 36 (16x32) tiles, A from hsA (xna), B from Wqkv
    for (int tt = wave; tt < 36; tt += 8) {
        const int rt = tt / 12, ct = tt - rt * 12;
        const int seg = ct >> 2;
        const int c0 = (ct & 3) * 32;
        const u16* bp = Wqkv + (size_t)(seg * 128 + c0 + col16) * 128 + quad * 8;
        f32x4 a0 = {0.f, 0.f, 0.f, 0.f}, a1 = a0;
        #pragma unroll
        for (int k0 = 0; k0 < 128; k0 += 32) {
            bf16x8 af = *(const bf16x8*)&hsA[(rt * 16 + col16) * 136 + k0 + quad * 8];
            bf16x8 b0 = *(const bf16x8*)(bp + k0);
            bf16x8 b1 = *(const bf16x8*)(bp + 16 * 128 + k0);
            a0 = MFMA16(af, b0, a0);
            a1 = MFMA16(af, b1, a1);
        }
        if (seg < 2) {
            const float* bias = seg == 0 ? bq : bk;
            const float sc = seg == 0 ? QS : 1.f;
            const float bv0 = bias[c0 + col16], bv1 = bias[c0 + 16 + col16];
            u16* o16 = seg == 0 ? q16 : k16;
            #pragma unroll
            for (int r = 0; r < 4; ++r) {
                const size_t gr = (size_t)(row0 + rt * 16 + quad * 4 + r) * 128;
                o16[gr + c0 + col16]      = f2bf((a0[r] + bv0) * sc);
                o16[gr + c0 + 16 + col16] = f2bf((a1[r] + bv1) * sc);
            }
        } else {
            const float bv0 = bv[c0 + col16], bv1 = bv[c0 + 16 + col16];
            const int bb = row0 / S, ssv = row0 - bb * S + rt * 16;
            const int ca = c0 + col16, cb = c0 + 16 + col16;
            u16* pa = vt16 + ((size_t)((bb * NH + (ca >> 5)) * 32 + (ca & 31))) * S + ssv;
            u16* pb = vt16 + ((size_t)((bb * NH + (cb >> 5)) * 32 + (cb & 31))) * S + ssv;
            #pragma unroll
            for (int r = 0; r < 4; ++r) {
                pa[quad * 4 + r] = f2bf(a0[r] + bv0);
                pb[quad * 4 + r] = f2bf(a1[r] + bv1);
            }
        }
    }
}

// ---------------------------------------------------------------- MFMA flash attention v4
// Block = (q-tile pair (p, 47-p), bh); 32-row Q-tiles; 4 waves split the key tiles.
// v4: 2-tile SOFTWARE PIPELINE per wave — pair (kt, kt+4) processed together so
// tile1's score MFMAs overlap tile0's exp2/LDS chain and PV(tile0) overlaps
// exp2(tile1). Dual per-wave P buffers. No-max softmax partials merge by ADDITION.
// Q pre-scaled by scale*log2e => p = exp2(score). O16 may alias Qb (single owner).
__global__ __launch_bounds__(256) void k_attn_mfma(
    const u16* Qb, const u16* __restrict__ Kb,
    const u16* __restrict__ Vt, u16* O16) {
    const int wave = threadIdx.x >> 6, lane = threadIdx.x & 63;
    const int p = blockIdx.x;        // 0..23
    const int bh = blockIdx.y;       // 0..31
    const int b = bh >> 2, hh = bh & 3;
    const int col = lane & 15, quad = lane >> 4;

    __shared__ __align__(16) u16 Pb[4][2][32][40];   // dual per-wave P tiles (20480 B)
    __shared__ float Om[4][32][33];                  // per-wave O partials
    __shared__ float Lm[4][32];                      // per-wave l partials
    u16 (* __restrict__ P0)[40] = Pb[wave][0];
    u16 (* __restrict__ P1)[40] = Pb[wave][1];

    const u16* Kbase = Kb + (size_t)b * S * 128 + hh * 32;
    const u16* Vbase = Vt + (size_t)bh * 32 * S;

    #pragma unroll
    for (int half = 0; half < 2; ++half) {
        const int qt = half == 0 ? p : 47 - p;
        const int q0 = qt * 32;
        const int nkt = qt + 1;
        const u16* qp = Qb + (size_t)(b * S + q0 + col) * 128 + hh * 32 + quad * 8;
        const bf16x8 qf0 = *(const bf16x8*)qp;
        const bf16x8 qf1 = *(const bf16x8*)(qp + 16 * 128);
        f32x4 o00 = {0.f, 0.f, 0.f, 0.f}, o01 = o00, o10 = o00, o11 = o00;
        float lsum[8] = {};

        for (int base = wave; base < nkt; base += 8) {
            const int kt0 = base, kt1 = base + 4;
            const bool has1 = (kt1 < nkt);       // wave-uniform branch
            // ---- loads for both tiles (independent; overlap following compute) ----
            const u16* kp0 = Kbase + (size_t)(kt0 * 32 + col) * 128 + quad * 8;
            const bf16x8 kA0 = *(const bf16x8*)kp0;
            const bf16x8 kA1 = *(const bf16x8*)(kp0 + 16 * 128);
            const u16* vp0 = Vbase + (size_t)col * S + kt0 * 32 + quad * 8;
            const bf16x8 vA0 = *(const bf16x8*)vp0;
            const bf16x8 vA1 = *(const bf16x8*)(vp0 + 16 * S);
            bf16x8 kB0 = {}, kB1 = {}, vB0 = {}, vB1 = {};
            if (has1) {
                const u16* kp1 = Kbase + (size_t)(kt1 * 32 + col) * 128 + quad * 8;
                kB0 = *(const bf16x8*)kp1;
                kB1 = *(const bf16x8*)(kp1 + 16 * 128);
                const u16* vp1 = Vbase + (size_t)col * S + kt1 * 32 + quad * 8;
                vB0 = *(const bf16x8*)vp1;
                vB1 = *(const bf16x8*)(vp1 + 16 * S);
            }
            const f32x4 z = {0.f, 0.f, 0.f, 0.f};
            // ---- scores tile0 ----
            f32x4 sA00 = MFMA16(qf0, kA0, z);
            f32x4 sA01 = MFMA16(qf0, kA1, z);
            f32x4 sA10 = MFMA16(qf1, kA0, z);
            f32x4 sA11 = MFMA16(qf1, kA1, z);
            // ---- scores tile1 (independent, overlaps exp(tile0)) ----
            f32x4 sB00, sB01, sB10, sB11;
            if (has1) {
                sB00 = MFMA16(qf0, kB0, z);
                sB01 = MFMA16(qf0, kB1, z);
                sB10 = MFMA16(qf1, kB0, z);
                sB11 = MFMA16(qf1, kB1, z);
            }
            // ---- exp + P write, tile0 ----
            {
                const bool diag = (kt0 == qt);
                const int k0g = kt0 * 32;
                #pragma unroll
                for (int r = 0; r < 4; ++r) {
                    const int lr = quad * 4 + r;
                    float p00 = fexp2(sA00[r]);
                    float p01 = fexp2(sA01[r]);
                    float p10 = fexp2(sA10[r]);
                    float p11 = fexp2(sA11[r]);
                    if (diag) {
                        const int qg0 = q0 + lr, qg1 = q0 + 16 + lr;
                        if (k0g + col > qg0)      p00 = 0.f;
                        if (k0g + 16 + col > qg0) p01 = 0.f;
                        if (k0g + col > qg1)      p10 = 0.f;
                        if (k0g + 16 + col > qg1) p11 = 0.f;
                    }
                    lsum[r]     += p00 + p01;
                    lsum[4 + r] += p10 + p11;
                    P0[lr][col]           = f2bf(p00);
                    P0[lr][16 + col]      = f2bf(p01);
                    P0[16 + lr][col]      = f2bf(p10);
                    P0[16 + lr][16 + col] = f2bf(p11);
                }
            }
            // ---- exp + P write, tile1 ----
            if (has1) {
                const bool diag = (kt1 == qt);
                const int k0g = kt1 * 32;
                #pragma unroll
                for (int r = 0; r < 4; ++r) {
                    const int lr = quad * 4 + r;
                    float p00 = fexp2(sB00[r]);
                    float p01 = fexp2(sB01[r]);
                    float p10 = fexp2(sB10[r]);
                    float p11 = fexp2(sB11[r]);
                    if (diag) {
                        const int qg0 = q0 + lr, qg1 = q0 + 16 + lr;
                        if (k0g + col > qg0)      p00 = 0.f;
                        if (k0g + 16 + col > qg0) p01 = 0.f;
                        if (k0g + col > qg1)      p10 = 0.f;
                        if (k0g + 16 + col > qg1) p11 = 0.f;
                    }
                    lsum[r]     += p00 + p01;
                    lsum[4 + r] += p10 + p11;
                    P1[lr][col]           = f2bf(p00);
                    P1[lr][16 + col]      = f2bf(p01);
                    P1[16 + lr][col]      = f2bf(p10);
                    P1[16 + lr][16 + col] = f2bf(p11);
                }
            }
            // ---- PV tile0 (in-wave LDS ordering; no barrier needed) ----
            {
                const bf16x8 pa0 = *(const bf16x8*)&P0[col][quad * 8];
                const bf16x8 pa1 = *(const bf16x8*)&P0[16 + col][quad * 8];
                o00 = MFMA16(pa0, vA0, o00);
                o01 = MFMA16(pa0, vA1, o01);
                o10 = MFMA16(pa1, vA0, o10);
                o11 = MFMA16(pa1, vA1, o11);
            }
            // ---- PV tile1 ----
            if (has1) {
                const bf16x8 pa0 = *(const bf16x8*)&P1[col][quad * 8];
                const bf16x8 pa1 = *(const bf16x8*)&P1[16 + col][quad * 8];
                o00 = MFMA16(pa0, vB0, o00);
                o01 = MFMA16(pa0, vB1, o01);
                o10 = MFMA16(pa1, vB0, o10);
                o11 = MFMA16(pa1, vB1, o11);
            }
        }
        #pragma unroll
        for (int i = 0; i < 8; ++i) {
            float v = lsum[i];
            v += __shfl_xor(v, 1); v += __shfl_xor(v, 2);
            v += __shfl_xor(v, 4); v += __shfl_xor(v, 8);
            lsum[i] = v;
        }
        #pragma unroll
        for (int r = 0; r < 4; ++r) {
            const int lr = quad * 4 + r;
            Om[wave][lr][col]           = o00[r];
            Om[wave][lr][16 + col]      = o01[r];
            Om[wave][16 + lr][col]      = o10[r];
            Om[wave][16 + lr][16 + col] = o11[r];
        }
        if (col == 0) {
            #pragma unroll
            for (int i = 0; i < 8; ++i)
                Lm[wave][(i >> 2) * 16 + quad * 4 + (i & 3)] = lsum[i];
        }
        __syncthreads();
        {
            const int tr = threadIdx.x >> 3, tc = (threadIdx.x & 7) * 4;
            const float inv = frcp(Lm[0][tr] + Lm[1][tr] + Lm[2][tr] + Lm[3][tr]);
            u16x4 outv;
            #pragma unroll
            for (int c = 0; c < 4; ++c) {
                const float o = Om[0][tr][tc + c] + Om[1][tr][tc + c] +
                                Om[2][tr][tc + c] + Om[3][tr][tc + c];
                outv[c] = f2bf(o * inv);
            }
            *(u16x4*)(O16 + (size_t)(b * S + q0 + tr) * 128 + hh * 32 + tc) = outv;
        }
        __syncthreads();   // Om/Lm/Pb reused by the second half
    }
}

// ---------------------------------------------------------------- merged Wo + FFN (32-row blocks)
template <bool LAST>
__global__ __launch_bounds__(256) void k_mho_ffn(
    const u16* __restrict__ ao, const u16* __restrict__ WoT, const float* __restrict__ bo,
    float* __restrict__ hio,
    const float* __restrict__ ga1, const float* __restrict__ gb1,
    const u16* __restrict__ W1T, const float* __restrict__ b1,
    const u16* __restrict__ W2T, const float* __restrict__ b2,
    const float* __restrict__ ga2, const float* __restrict__ gb2, u16* __restrict__ xnout,
    const float* __restrict__ outW, const float* __restrict__ outb, float* __restrict__ outp) {
    __shared__ float hL[32 * 132];              // 16896 B (persists)
    __shared__ __align__(16) u16 xnL[32 * 136]; // 8704 B (ln_ff out)
    __shared__ __align__(16) u16 Ls[32 * 520];  // 33280 B (ff1 out)
    const int tid = threadIdx.x;
    const int wave = tid >> 6, lane = tid & 63;
    const int col16 = lane & 15, quad = lane >> 4;
    const int row0 = blockIdx.x * 32;
    const int c0 = wave * 32;

    // Wo GEMM (K=128)
    {
        const u16* a0p = ao + (size_t)(row0 + col16) * 128 + quad * 8;
        const u16* b0p = WoT + (size_t)(c0 + col16) * 128 + quad * 8;
        f32x4 acc00 = {0.f, 0.f, 0.f, 0.f}, acc01 = acc00, acc10 = acc00, acc11 = acc00;
        mfma_tile32<128>(a0p, a0p + 16 * 128, b0p, b0p + 16 * 128, acc00, acc01, acc10, acc11);
        const float bv0 = bo[c0 + col16];
        const float bv1 = bo[c0 + 16 + col16];
        #pragma unroll
        for (int r = 0; r < 4; ++r) {
            const int l0 = quad * 4 + r, l1 = 16 + quad * 4 + r;
            const size_t g0 = (size_t)(row0 + l0) * D, g1 = (size_t)(row0 + l1) * D;
            hL[l0 * 132 + c0 + col16]      = acc00[r] + bv0 + hio[g0 + c0 + col16];
            hL[l0 * 132 + c0 + 16 + col16] = acc01[r] + bv1 + hio[g0 + c0 + 16 + col16];
            hL[l1 * 132 + c0 + col16]      = acc10[r] + bv0 + hio[g1 + c0 + col16];
            hL[l1 * 132 + c0 + 16 + col16] = acc11[r] + bv1 + hio[g1 + c0 + 16 + col16];
        }
    }
    __syncthreads();
    // ln_ff -> xnL (bf16)
    {
        const int r = tid >> 3, cg = (tid & 7) * 16;
        float vals[16];
        #pragma unroll
        for (int jj = 0; jj < 4; ++jj) {
            float4 v = *(const float4*)&hL[r * 132 + cg + 4 * jj];
            vals[4 * jj] = v.x; vals[4 * jj + 1] = v.y; vals[4 * jj + 2] = v.z; vals[4 * jj + 3] = v.w;
        }
        float s = 0.f;
        #pragma unroll
        for (int j = 0; j < 16; ++j) s += vals[j];
        s += __shfl_xor(s, 1); s += __shfl_xor(s, 2); s += __shfl_xor(s, 4);
        const float mean = s * (1.f / D);
        float q = 0.f;
        #pragma unroll
        for (int j = 0; j < 16; ++j) { float d = vals[j] - mean; q += d * d; }
        q += __shfl_xor(q, 1); q += __shfl_xor(q, 2); q += __shfl_xor(q, 4);
        const float inv = frcp(sqrtf(q * (1.f / (D - 1))) + EPS);
        #pragma unroll
        for (int jj = 0; jj < 4; ++jj) {
            u16x4 o;
            #pragma unroll
            for (int c = 0; c < 4; ++c)
                o[c] = f2bf(ga1[cg + 4 * jj + c] * (vals[4 * jj + c] - mean) * inv + gb1[cg + 4 * jj + c]);
            *(u16x4*)&xnL[r * 136 + cg + 4 * jj] = o;
        }
    }
    __syncthreads();
    // FF1: wave computes cols [wave*128, +128), A from xnL
    #pragma unroll
    for (int ct = 0; ct < 4; ++ct) {
        const int c0f = wave * 128 + ct * 32;
        const u16* b0p = W1T + (size_t)(c0f + col16) * 128 + quad * 8;
        f32x4 acc00 = {0.f, 0.f, 0.f, 0.f}, acc01 = acc00, acc10 = acc00, acc11 = acc00;
        #pragma unroll
        for (int k0 = 0; k0 < 128; k0 += 32) {
            bf16x8 a0 = *(const bf16x8*)&xnL[col16 * 136 + k0 + quad * 8];
            bf16x8 a1 = *(const bf16x8*)&xnL[(16 + col16) * 136 + k0 + quad * 8];
            bf16x8 b0 = *(const bf16x8*)(b0p + k0);
            bf16x8 b1 = *(const bf16x8*)(b0p + 16 * 128 + k0);
            acc00 = MFMA16(a0, b0, acc00);
            acc01 = MFMA16(a0, b1, acc01);
            acc10 = MFMA16(a1, b0, acc10);
            acc11 = MFMA16(a1, b1, acc11);
        }
        const float bv0 = b1[c0f + col16];
        const float bv1 = b1[c0f + 16 + col16];
        #pragma unroll
        for (int r = 0; r < 4; ++r) {
            const int l0 = quad * 4 + r, l1 = 16 + quad * 4 + r;
            Ls[l0 * 520 + c0f + col16]      = f2bf(fmaxf(acc00[r] + bv0, 0.f));
            Ls[l0 * 520 + c0f + 16 + col16] = f2bf(fmaxf(acc01[r] + bv1, 0.f));
            Ls[l1 * 520 + c0f + col16]      = f2bf(fmaxf(acc10[r] + bv0, 0.f));
            Ls[l1 * 520 + c0f + 16 + col16] = f2bf(fmaxf(acc11[r] + bv1, 0.f));
        }
    }
    __syncthreads();
    // FF2: wave computes out cols [wave*32, +32), K=512 from Ls
    {
        f32x4 acc00 = {0.f, 0.f, 0.f, 0.f}, acc01 = acc00, acc10 = acc00, acc11 = acc00;
        #pragma unroll
        for (int k0 = 0; k0 < 512; k0 += 32) {
            bf16x8 a0 = *(const bf16x8*)&Ls[col16 * 520 + k0 + quad * 8];
            bf16x8 a1 = *(const bf16x8*)&Ls[(16 + col16) * 520 + k0 + quad * 8];
            const u16* bp = W2T + (size_t)(c0 + col16) * 512 + k0 + quad * 8;
            bf16x8 b0 = *(const bf16x8*)bp;
            bf16x8 b1v = *(const bf16x8*)(bp + 16 * 512);
            acc00 = MFMA16(a0, b0, acc00);
            acc01 = MFMA16(a0, b1v, acc01);
            acc10 = MFMA16(a1, b0, acc10);
            acc11 = MFMA16(a1, b1v, acc11);
        }
        const float bv0 = b2[c0 + col16];
        const float bv1 = b2[c0 + 16 + col16];
        #pragma unroll
        for (int r = 0; r < 4; ++r) {
            const int l0 = quad * 4 + r, l1 = 16 + quad * 4 + r;
            const size_t g0 = (size_t)(row0 + l0) * D, g1 = (size_t)(row0 + l1) * D;
            const float v00 = acc00[r] + bv0 + hL[l0 * 132 + c0 + col16];
            const float v01 = acc01[r] + bv1 + hL[l0 * 132 + c0 + 16 + col16];
            const float v10 = acc10[r] + bv0 + hL[l1 * 132 + c0 + col16];
            const float v11 = acc11[r] + bv1 + hL[l1 * 132 + c0 + 16 + col16];
            hio[g0 + c0 + col16]      = v00;
            hio[g0 + c0 + 16 + col16] = v01;
            hio[g1 + c0 + col16]      = v10;
            hio[g1 + c0 + 16 + col16] = v11;
            hL[l0 * 132 + c0 + col16]      = v00;
            hL[l0 * 132 + c0 + 16 + col16] = v01;
            hL[l1 * 132 + c0 + col16]      = v10;
            hL[l1 * 132 + c0 + 16 + col16] = v11;
        }
    }
    __syncthreads();
    // tail
    {
        const int r = tid >> 3, cg = (tid & 7) * 16;
        float vals[16];
        #pragma unroll
        for (int jj = 0; jj < 4; ++jj) {
            float4 v = *(const float4*)&hL[r * 132 + cg + 4 * jj];
            vals[4 * jj] = v.x; vals[4 * jj + 1] = v.y; vals[4 * jj + 2] = v.z; vals[4 * jj + 3] = v.w;
        }
        if constexpr (LAST) {
            float dot = 0.f;
            #pragma unroll
            for (int j = 0; j < 16; ++j) dot += vals[j] * outW[cg + j];
            dot += __shfl_xor(dot, 1); dot += __shfl_xor(dot, 2); dot += __shfl_xor(dot, 4);
            if ((tid & 7) == 0) outp[row0 + r] = sigmoidf_(dot + outb[0]);
        } else {
            float s = 0.f;
            #pragma unroll
            for (int j = 0; j < 16; ++j) s += vals[j];
            s += __shfl_xor(s, 1); s += __shfl_xor(s, 2); s += __shfl_xor(s, 4);
            const float mean = s * (1.f / D);
            float q = 0.f;
            #pragma unroll
            for (int j = 0; j < 16; ++j) { float d = vals[j] - mean; q += d * d; }
            q += __shfl_xor(q, 1); q += __shfl_xor(q, 2); q += __shfl_xor(q, 4);
            const float inv = frcp(sqrtf(q * (1.f / (D - 1))) + EPS);
            u16* xp = xnout + (size_t)(row0 + r) * D + cg;
            #pragma unroll
            for (int jj = 0; jj < 4; ++jj) {
                u16x4 o;
                #pragma unroll
                for (int c = 0; c < 4; ++c)
                    o[c] = f2bf(ga2[cg + 4 * jj + c] * (vals[4 * jj + c] - mean) * inv + gb2[cg + 4 * jj + c]);
                *(u16x4*)(xp + 4 * jj) = o;
            }
        }
    }
}

// ---------------------------------------------------------------- host
extern "C" void kernel_launch(void* const* d_in, const int* in_sizes, int n_in,
                              void* d_out, int out_size, void* d_ws, size_t ws_size,
                              hipStream_t stream) {
    const float* x       = (const float*)d_in[0];
    const float* enc_W   = (const float*)d_in[1];
    const float* enc_b   = (const float*)d_in[2];
    const float* ln_rnn_a = (const float*)d_in[3];
    const float* ln_rnn_b = (const float*)d_in[4];
    const float* gru_Wih = (const float*)d_in[5];
    const float* gru_Whh = (const float*)d_in[6];
    const float* gru_bih = (const float*)d_in[7];
    const float* gru_bhh = (const float*)d_in[8];
    const float* ln_attn_a = (const float*)d_in[9];
    const float* ln_attn_b = (const float*)d_in[10];
    const float* Wq = (const float*)d_in[11];
    const float* bq = (const float*)d_in[12];
    const float* Wk = (const float*)d_in[13];
    const float* bk = (const float*)d_in[14];
    const float* Wv = (const float*)d_in[15];
    const float* bv = (const float*)d_in[16];
    const float* Wo = (const float*)d_in[17];
    const float* bo = (const float*)d_in[18];
    const float* ln_ff_a = (const float*)d_in[19];
    const float* ln_ff_b = (const float*)d_in[20];
    const float* ff_W1 = (const float*)d_in[21];
    const float* ff_b1 = (const float*)d_in[22];
    const float* ff_W2 = (const float*)d_in[23];
    const float* ff_b2 = (const float*)d_in[24];
    const float* out_W = (const float*)d_in[25];
    const float* out_b = (const float*)d_in[26];

    float* h   = (float*)d_ws;                 // MD f32
    u16* pool  = (u16*)(h + MD);               // 3*MD u16 (q|k|vt)
    u16* xn16  = pool + (size_t)3 * MD;        // MD u16 (ln_rnn outputs)
    u16* Wih16 = xn16 + MD;
    u16* Whh16 = Wih16 + NLVL * 384 * D;
    u16* Wqkv  = Whh16 + NLVL * 384 * D;       // [lvl][384][128]
    u16* WoT   = Wqkv + NLVL * 384 * D;
    u16* W1T   = WoT + NLVL * D * D;           // [lvl][512][128]
    u16* W2T   = W1T + NLVL * D * DFF;         // [lvl][128][512]

    u16* q16   = pool;                         // Q; attention output overwrites it
    u16* k16   = pool + MD;
    u16* vt16  = pool + (size_t)2 * MD;
    u16* ao16  = q16;                          // attention output (aliases Q; safe)

    k_prep_enc<<<2688, 256, 0, stream>>>(
        gru_Wih, gru_Whh, Wq, Wk, Wv, Wo, ff_W1, ff_W2,
        Wih16, Whh16, Wqkv, WoT, W1T, W2T,
        x, enc_W, enc_b, ln_rnn_a, ln_rnn_b, h, xn16);

    for (int lvl = 0; lvl < NLVL; ++lvl) {
        // --- LocalRNN + ln_attn + QKV (one kernel; 256 blocks x 48 rows, 2 blocks/CU) ---
        k_gru_qkv<<<M / 48, 512, 0, stream>>>(
            xn16, Wih16 + lvl * 384 * D, Whh16 + lvl * 384 * D,
            gru_bih + lvl * 384, gru_bhh + lvl * 384,
            h, ln_attn_a + lvl * D, ln_attn_b + lvl * D,
            Wqkv + lvl * 384 * D, bq + lvl * D, bk + lvl * D, bv + lvl * D,
            q16, k16, vt16);

        // --- attention (v4: 2-tile pipelined) ---
        k_attn_mfma<<<dim3(24, 32), 256, 0, stream>>>(q16, k16, vt16, ao16);

        // --- Wo + FFN merged (fuses next ln_rnn or the output head) ---
        if (lvl + 1 < NLVL) {
            k_mho_ffn<false><<<M / 32, 256, 0, stream>>>(
                ao16, WoT + lvl * D * D, bo + lvl * D, h,
                ln_ff_a + lvl * D, ln_ff_b + lvl * D,
                W1T + lvl * D * DFF, ff_b1 + lvl * DFF,
                W2T + lvl * DFF * D, ff_b2 + lvl * D,
                ln_rnn_a + (lvl + 1) * D, ln_rnn_b + (lvl + 1) * D, xn16,
                nullptr, nullptr, nullptr);
        } else {
            k_mho_ffn<true><<<M / 32, 256, 0, stream>>>(
                ao16, WoT + lvl * D * D, bo + lvl * D, h,
                ln_ff_a + lvl * D, ln_ff_b + lvl * D,
                W1T + lvl * D * DFF, ff_b1 + lvl * DFF,
                W2T + lvl * DFF * D, ff_b2 + lvl * D,
                nullptr, nullptr, nullptr,
                out_W, out_b, (float*)d_out);
        }
    }
}